// Round 10
// baseline (634.173 us; speedup 1.0000x reference)
//
#include <hip/hip_runtime.h>
#include <hip/hip_bf16.h>
#include <stdint.h>

#define S 2048
#define D 64
#define H 4096
#define NB 8

typedef __bf16 bf16;
typedef __attribute__((ext_vector_type(8))) __bf16 bf16x8;
typedef __attribute__((ext_vector_type(4))) __bf16 bf16x4;
typedef __attribute__((ext_vector_type(4))) float f32x4;

// Raw LDS-DMA, invisible to the compiler's waitcnt pass (no auto vmcnt(0)).
// M0 = wave-uniform LDS byte offset; HW adds lane*16B. (R5-verified.)
__device__ __forceinline__ void dma16_raw(const bf16* g, uint32_t m0_bytes) {
  uint32_t m0s = __builtin_amdgcn_readfirstlane(m0_bytes);
  asm volatile("s_mov_b32 m0, %1\n\t"
               "global_load_lds_dwordx4 %0, off"
               :: "v"(g), "s"(m0s) : "memory");
}

__device__ __forceinline__ uint32_t lds_off_bytes(const void* p) {
  return (uint32_t)(uintptr_t)(__attribute__((address_space(3))) const void*)p;
}

// ---------------------------------------------------------------------------
// mega_prep (R16): ONE preamble dispatch replacing {W1 transpose, W2
// transpose, Q/K cast, all-NB V transpose}. Role decode on blockIdx.x.
// ---------------------------------------------------------------------------
__global__ __launch_bounds__(256) void mega_prep(
    const float* __restrict__ W1, bf16* __restrict__ W1t,
    const float* __restrict__ W2, bf16* __restrict__ W2t,
    const float* __restrict__ Q, bf16* __restrict__ Qb,
    const float* __restrict__ Km, bf16* __restrict__ Kb,
    const float* __restrict__ V, bf16* __restrict__ VtAll) {
  __shared__ float tile[64][65];
  int b = blockIdx.x;
  int tid = threadIdx.x;
  int c4 = (tid & 15) * 4;
  int r16 = tid >> 4;

  if (b < 4096) {
    // ---- transpose+cast role (R14 vectorized body) ----
    const float* W; bf16* Wt; int K, N, x, y;
    if (b < 2048) { W = W1; Wt = W1t; K = S; N = H; x = b & 63; y = b >> 6; }
    else { int t = b - 2048; W = W2; Wt = W2t; K = H; N = S; x = t & 31; y = t >> 5; }
    int k0 = y * 64, n0 = x * 64;
#pragma unroll
    for (int i = 0; i < 4; ++i) {
      int r = i * 16 + r16;
      f32x4 v = *(const f32x4*)&W[(size_t)(k0 + r) * N + n0 + c4];
      tile[r][c4 + 0] = v.x; tile[r][c4 + 1] = v.y;
      tile[r][c4 + 2] = v.z; tile[r][c4 + 3] = v.w;
    }
    __syncthreads();
#pragma unroll
    for (int i = 0; i < 4; ++i) {
      int n = i * 16 + r16;
      bf16x4 o;
      o[0] = (bf16)tile[c4 + 0][n]; o[1] = (bf16)tile[c4 + 1][n];
      o[2] = (bf16)tile[c4 + 2][n]; o[3] = (bf16)tile[c4 + 3][n];
      *(bf16x4*)&Wt[(size_t)(n0 + n) * K + k0 + c4] = o;
    }
  } else if (b < 6144) {
    // ---- elementwise cast role (Q then K) ----
    int t = b - 4096;
    const float* x = (t >> 10) ? Km : Q;
    bf16* y = (t >> 10) ? Kb : Qb;
    int i = (t & 1023) * 256 + tid;
    f32x4 v = ((const f32x4*)x)[i];
    bf16x4 o;
    o[0] = (bf16)v.x; o[1] = (bf16)v.y; o[2] = (bf16)v.z; o[3] = (bf16)v.w;
    ((bf16x4*)y)[i] = o;
  } else {
    // ---- V transpose role (all NB batches, hoisted-Vt mode only) ----
    int t = b - 6144;  // 0..NB*32-1
    int s0 = (t & 31) * 64;
    int z = t >> 5;
    const float* Vb = V + (size_t)z * (S * D);
    bf16* Vtb = VtAll + (size_t)z * (D * S);
#pragma unroll
    for (int i = 0; i < 4; ++i) {
      int r = i * 16 + r16;  // s-row within tile
      f32x4 v = *(const f32x4*)&Vb[(size_t)(s0 + r) * D + c4];
      tile[r][c4 + 0] = v.x; tile[r][c4 + 1] = v.y;
      tile[r][c4 + 2] = v.z; tile[r][c4 + 3] = v.w;
    }
    __syncthreads();
#pragma unroll
    for (int i = 0; i < 4; ++i) {
      int n = i * 16 + r16;  // d index
      bf16x4 o;
      o[0] = (bf16)tile[c4 + 0][n]; o[1] = (bf16)tile[c4 + 1][n];
      o[2] = (bf16)tile[c4 + 2][n]; o[3] = (bf16)tile[c4 + 3][n];
      *(bf16x4*)&Vtb[(size_t)n * S + s0 + c4] = o;
    }
  }
}

// ---------------------------------------------------------------------------
// vt_cast: per-group V transpose — FALLBACK path only (workspace too small
// for the dedicated all-NB Vt region; writes into the dead h region).
// ---------------------------------------------------------------------------
__global__ __launch_bounds__(256) void vt_cast(const float* __restrict__ V,
                                               bf16* __restrict__ Vt) {
  __shared__ float tile[64][65];
  int z = blockIdx.y;
  int s0 = blockIdx.x * 64;
  const float* Vb = V + (size_t)z * (S * D);
  bf16* Vtb = Vt + (size_t)z * (D * S);
  int c4 = (threadIdx.x & 15) * 4;
  int r16 = threadIdx.x >> 4;
#pragma unroll
  for (int i = 0; i < 4; ++i) {
    int r = i * 16 + r16;
    f32x4 v = *(const f32x4*)&Vb[(size_t)(s0 + r) * D + c4];
    tile[r][c4 + 0] = v.x; tile[r][c4 + 1] = v.y;
    tile[r][c4 + 2] = v.z; tile[r][c4 + 3] = v.w;
  }
  __syncthreads();
#pragma unroll
  for (int i = 0; i < 4; ++i) {
    int n = i * 16 + r16;
    bf16x4 o;
    o[0] = (bf16)tile[c4 + 0][n]; o[1] = (bf16)tile[c4 + 1][n];
    o[2] = (bf16)tile[c4 + 2][n]; o[3] = (bf16)tile[c4 + 3][n];
    *(bf16x4*)&Vtb[(size_t)n * S + s0 + c4] = o;
  }
}

// ---------------------------------------------------------------------------
// qk_bt (R17): specialized QK^T GEMM. Replaces the generic gemm_bt, whose
// deep-K loop machinery at K=64 (niter=2) re-staged the last tile twice
// (24 redundant DMAs/block, 2x A/B traffic) and paid 4 barriers where the
// dependency structure needs 2. Here: stage BOTH K-tiles up front ->
// vmcnt(6)+bar (tile0 rendezvous, tile1 in flight) -> 32 MFMA ->
// vmcnt(0)+bar (tile1 rendezvous, all DMAs drained) -> 32 MFMA -> store.
// Staging layout / swizzle / per-acc MFMA order identical to the verified
// gemm_bt -> bit-identical numerics. Sc = (Q @ K^T) * 0.125, bf16 out.
// ---------------------------------------------------------------------------
__global__ __launch_bounds__(256, 2) void qk_bt(const bf16* __restrict__ Qb,
                                                const bf16* __restrict__ Kb,
                                                bf16* __restrict__ Sc) {
  __shared__ __align__(16) bf16 smem[24576];
  int tid = threadIdx.x;
  int lane = tid & 63;
  int w = tid >> 6;

  int m0 = blockIdx.y * 128, n0 = blockIdx.x * 256;
  const bf16* Ab = Qb + (size_t)blockIdx.z * (S * D);
  const bf16* Btb = Kb + (size_t)blockIdx.z * (S * D);

  int grow = tid >> 2;
  int gcol = (((lane & 3) ^ ((lane >> 3) & 3)) * 8);
  const bf16* gA0 = Ab + (size_t)(m0 + grow) * D + gcol;
  const bf16* gA1 = gA0 + (size_t)64 * D;
  const bf16* gB0 = Btb + (size_t)(n0 + grow) * D + gcol;
  const bf16* gB1 = gB0 + (size_t)64 * D;
  const bf16* gB2 = gB0 + (size_t)128 * D;
  const bf16* gB3 = gB0 + (size_t)192 * D;

  uint32_t ldsBase = lds_off_bytes(&smem[0]);
  uint32_t wb = (uint32_t)(w * 1024);
  uint32_t mA[2], mB[2];
  mA[0] = ldsBase + wb;          mA[1] = ldsBase + 8192 + wb;
  mB[0] = ldsBase + 16384 + wb;  mB[1] = ldsBase + 32768 + wb;

  int mw = (w & 1) * 64, nw = (w >> 1) * 128;
  int lr = lane & 15;
  int ck = lane >> 4;
  int swz = (ck ^ ((lr >> 1) & 3)) * 8;
  const bf16* paBase = smem + (size_t)(mw + lr) * 32 + swz;
  const bf16* pbBase = smem + 8192 + (size_t)(nw + lr) * 32 + swz;

  f32x4 zero = {0.f, 0.f, 0.f, 0.f};
  f32x4 acc[4][8];
#pragma unroll
  for (int mt = 0; mt < 4; ++mt)
#pragma unroll
    for (int nt = 0; nt < 8; ++nt) acc[mt][nt] = zero;

#define STAGE(buf, koff)                                 \
  do {                                                   \
    dma16_raw(gA0 + (koff), mA[buf]);                    \
    dma16_raw(gA1 + (koff), mA[buf] + 4096);             \
    dma16_raw(gB0 + (koff), mB[buf]);                    \
    dma16_raw(gB1 + (koff), mB[buf] + 4096);             \
    dma16_raw(gB2 + (koff), mB[buf] + 8192);             \
    dma16_raw(gB3 + (koff), mB[buf] + 12288);            \
  } while (0)

  STAGE(0, 0);
  STAGE(1, 32);
#undef STAGE

#pragma unroll
  for (int it = 0; it < 2; ++it) {
    if (it == 0)
      asm volatile("s_waitcnt vmcnt(6)\n\ts_barrier" ::: "memory");
    else
      asm volatile("s_waitcnt vmcnt(0)\n\ts_barrier" ::: "memory");
    const bf16* pa = paBase + it * 4096;
    const bf16* pb = pbBase + it * 8192;
    bf16x8 af[4], bfr[8];
#pragma unroll
    for (int mt = 0; mt < 4; ++mt) af[mt] = *(const bf16x8*)(pa + mt * (16 * 32));
#pragma unroll
    for (int nt = 0; nt < 8; ++nt) bfr[nt] = *(const bf16x8*)(pb + nt * (16 * 32));
#pragma unroll
    for (int mt = 0; mt < 4; ++mt)
#pragma unroll
      for (int nt = 0; nt < 8; ++nt)
        acc[mt][nt] = __builtin_amdgcn_mfma_f32_16x16x32_bf16(af[mt], bfr[nt],
                                                              acc[mt][nt], 0, 0, 0);
  }

  bf16* C = Sc + (size_t)blockIdx.z * (S * S);
  int mbase = m0 + mw + (lane >> 4) * 4;
  int nbase = n0 + nw + (lane & 15);
#pragma unroll
  for (int mt = 0; mt < 4; ++mt) {
#pragma unroll
    for (int nt = 0; nt < 8; ++nt) {
      int n = nbase + nt * 16;
#pragma unroll
      for (int reg = 0; reg < 4; ++reg) {
        int m = mbase + mt * 16 + reg;
        C[(size_t)m * S + n] = (bf16)(acc[mt][nt][reg] * 0.125f);
      }
    }
  }
}

// ---------------------------------------------------------------------------
// gemm256: R13 rotated 4-barrier counted-vmcnt schedule. VERIFIED BEST:
// ~117 us, MfmaUtil 52%, 0 conflicts. Schedule-lever search CLOSED
// (R8/R10/R11/R13/R14 measured; alternatives closed by register/LDS/race
// arithmetic — see R15/R17 history). Ceiling model: per CU-tile MFMA floor
// 2483 cyc vs LDS traffic ~2300-3000 cyc -> max ~55-62% util at this
// fragment shape; we measure 52%.
// Do not change fragment read pattern / stage order / vmcnt placement
// without re-measuring SQ_LDS_BANK_CONFLICT and re-deriving the R8 RAW
// invariant (at each tile-boundary vmcnt(4), exactly the two tile+2
// half-stages are outstanding).
// ---------------------------------------------------------------------------
template <int RELU, int OUTBF16>
__global__ __launch_bounds__(512, 2) void gemm256(const bf16* __restrict__ A,
                                                  const bf16* __restrict__ Bt,
                                                  const float* __restrict__ bias,
                                                  void* __restrict__ Cv,
                                                  float scale,
                                                  int M, int N, int K,
                                                  long strideA, long strideB,
                                                  long strideC) {
  __shared__ __align__(16) bf16 smem[65536];  // 128 KiB
  const char* smc = (const char*)&smem[0];

  int tid = threadIdx.x;
  int lane = tid & 63;
  int w = tid >> 6;
  int wm = w >> 2, wn = w & 3;  // 2M x 4N wave grid

  unsigned gx = gridDim.x;
  unsigned nwg = gx * gridDim.y;
  unsigned flat = blockIdx.y * gx + blockIdx.x;
  unsigned q = nwg >> 3, r = nwg & 7, xcd = flat & 7, idx = flat >> 3;
  unsigned wg = (xcd < r ? xcd * (q + 1) : r * (q + 1) + (xcd - r) * q) + idx;
  int n0 = (int)(wg % gx) * 256;
  int m0 = (int)(wg / gx) * 256;

  const bf16* Ab = A + (size_t)blockIdx.z * strideA;
  const bf16* Btb = Bt + (size_t)blockIdx.z * strideB;

  int trow = tid >> 3;
  int tg = (tid & 7) ^ (trow & 7);
  const bf16* pgA = Ab + (size_t)(m0 + trow) * K + tg * 8;
  const bf16* pgB = Btb + (size_t)(n0 + trow) * K + tg * 8;
  const size_t s64K = (size_t)K * 64;

  uint32_t ldsBase = lds_off_bytes(&smem[0]);
  uint32_t mb = ldsBase + (uint32_t)(w * 1024);

  int j = lane >> 4, b2 = (lane >> 2) & 1;
  uint32_t rbA0 = (uint32_t)(wm * 8192 + (lane & 15) * 128 +
                             ((j ^ (lane & 3)) * 16) + b2 * 64);
  uint32_t rbA1 = rbA0 ^ 64u;
  uint32_t rbB0 = (uint32_t)(65536 + wn * 4096 + (lane & 15) * 128 +
                             ((j ^ (lane & 3)) * 16) + b2 * 64);
  uint32_t rbB1 = rbB0 ^ 64u;

  f32x4 acc[8][4];
#pragma unroll
  for (int a = 0; a < 8; ++a)
#pragma unroll
    for (int b = 0; b < 2 * 2; ++b) acc[a][b] = (f32x4){0.f, 0.f, 0.f, 0.f};

  bf16x8 af[4][2];
  bf16x8 bf0[2][2];
  bf16x8 bf1[2][2];

#define STG_A(PI, HH, LL, KC) \
  dma16_raw(pgA + (size_t)(2 * (HH) + (LL)) * s64K + (KC), \
            mb + (PI) * 32768 + (HH) * 16384 + (LL) * 8192)
#define STG_B(PI, HH, LL, KC) \
  dma16_raw(pgB + (size_t)(2 * (HH) + (LL)) * s64K + (KC), \
            mb + 65536 + (PI) * 32768 + (HH) * 16384 + (LL) * 8192)
#define STAGE_AH(PI, HH, KC) do { STG_A(PI, HH, 0, KC); STG_A(PI, HH, 1, KC); } while (0)
#define STAGE_BH(PI, HH, KC) do { STG_B(PI, HH, 0, KC); STG_B(PI, HH, 1, KC); } while (0)

#define RDA(PI, QA)                                                            \
  do {                                                                        \
    _Pragma("unroll") for (int mt = 0; mt < 4; ++mt) {                        \
      af[mt][0] = *(const bf16x8*)(smc + rbA0 + ((PI) * 32768 + (QA) * 16384 + mt * 2048)); \
      af[mt][1] = *(const bf16x8*)(smc + rbA1 + ((PI) * 32768 + (QA) * 16384 + mt * 2048)); \
    }                                                                         \
  } while (0)
#define RDB(PI, QB, BF)                                                        \
  do {                                                                        \
    _Pragma("unroll") for (int nt = 0; nt < 2; ++nt) {                        \
      BF[nt][0] = *(const bf16x8*)(smc + rbB0 + ((PI) * 32768 + (QB) * 16384 + nt * 2048)); \
      BF[nt][1] = *(const bf16x8*)(smc + rbB1 + ((PI) * 32768 + (QB) * 16384 + nt * 2048)); \
    }                                                                         \
  } while (0)

#define MFMA_Q(QA, QB, BF)                                                     \
  do {                                                                        \
    __builtin_amdgcn_s_setprio(1);                                            \
    _Pragma("unroll") for (int mt = 0; mt < 4; ++mt)                          \
      _Pragma("unroll") for (int nt = 0; nt < 2; ++nt) {                      \
        f32x4 c = acc[(QA) * 4 + mt][(QB) * 2 + nt];                          \
        c = __builtin_amdgcn_mfma_f32_16x16x32_bf16(af[mt][0], BF[nt][0], c, 0, 0, 0); \
        c = __builtin_amdgcn_mfma_f32_16x16x32_bf16(af[mt][1], BF[nt][1], c, 0, 0, 0); \
        acc[(QA) * 4 + mt][(QB) * 2 + nt] = c;                                \
      }                                                                       \
    __builtin_amdgcn_s_setprio(0);                                            \
  } while (0)

#define BAR() asm volatile("s_barrier" ::: "memory")
#define VMC4() asm volatile("s_waitcnt vmcnt(4)" ::: "memory")

#define TILE2(PI, TT)                                              \
  do {                                                             \
    int c1 = ((TT) + 1 < NT ? (TT) + 1 : NT - 1) * 64;             \
    int c2 = ((TT) + 2 < NT ? (TT) + 2 : NT - 1) * 64;             \
    MFMA_Q(0, 0, bf0);                                             \
    RDB(PI, 1, bf1);                                               \
    STAGE_BH((PI) ^ 1, 0, c1);                                     \
    BAR();                                                         \
    MFMA_Q(0, 1, bf1);                                             \
    RDA(PI, 1);                                                    \
    STAGE_AH(PI, 0, c2);                                           \
    BAR();                                                         \
    STAGE_BH(PI, 1, c2);                                           \
    MFMA_Q(1, 1, bf1);                                             \
    VMC4();                                                        \
    BAR();                                                         \
    MFMA_Q(1, 0, bf0);                                             \
    if ((TT) + 1 < NT) {                                           \
      RDA((PI) ^ 1, 0);                                            \
      RDB((PI) ^ 1, 0, bf0);                                       \
      STAGE_AH(PI, 1, c2);                                         \
      BAR();                                                       \
    }                                                              \
  } while (0)

  STAGE_AH(0, 0, 0);
  STAGE_BH(0, 1, 0);
  STAGE_AH(0, 1, 0);
  STAGE_BH(0, 0, 0);
  STAGE_AH(1, 0, 64);
  STAGE_BH(1, 1, 64);
  asm volatile("s_waitcnt vmcnt(4)\n\ts_barrier" ::: "memory");

  const int NT = K / 64;

  RDA(0, 0);
  RDB(0, 0, bf0);
  STAGE_AH(1, 1, 64);
  BAR();

  for (int T = 0; T < NT; T += 2) {
    TILE2(0, T);
    TILE2(1, T + 1);
  }
#undef TILE2
#undef VMC4
#undef BAR
#undef MFMA_Q
#undef RDB
#undef RDA
#undef STAGE_BH
#undef STAGE_AH
#undef STG_B
#undef STG_A

  asm volatile("s_waitcnt vmcnt(0)" ::: "memory");

  int rowb = m0 + wm * 64 + ((lane >> 4) << 2);
  int colb = n0 + wn * 32 + (lane & 15);
#pragma unroll
  for (int fn = 0; fn < 4; ++fn) {
    int n = colb + (fn >> 1) * 128 + (fn & 1) * 16;
    float bv = bias ? bias[n] : 0.f;
#pragma unroll
    for (int fm = 0; fm < 8; ++fm) {
      int mrow = rowb + (fm >> 2) * 128 + (fm & 3) * 16;
#pragma unroll
      for (int reg = 0; reg < 4; ++reg) {
        float v = acc[fm][fn][reg] * scale + bv;
        if (RELU) v = fmaxf(v, 0.f);
        int m = mrow + reg;
        if (OUTBF16) {
          bf16* C = (bf16*)Cv + (size_t)blockIdx.z * strideC;
          C[(size_t)m * N + n] = (bf16)v;
        } else {
          float* C = (float*)Cv + (size_t)blockIdx.z * strideC;
          C[(size_t)m * N + n] = v;
        }
      }
    }
  }
}

// ---------------------------------------------------------------------------
// smav: fused softmax + attn@V on MFMA (R9; replaced 128us scalar AV).
// ---------------------------------------------------------------------------
__global__ __launch_bounds__(256) void smav(const float* __restrict__ adj,
                                            const bf16* __restrict__ Vt,
                                            float* __restrict__ out,
                                            long adjStride) {
  int z = blockIdx.y;
  const float* adjb = adj + (size_t)z * adjStride;
  const bf16* Vtb = Vt + (size_t)z * (D * S);
  float* outb = out + (size_t)z * (S * D);
  int q0 = blockIdx.x * 16;
  __shared__ __align__(16) bf16 P[16 * 2048];  // 64 KiB, swizzled
  __shared__ float rsum[16];
  int tid = threadIdx.x, w = tid >> 6, lane = tid & 63;
  char* Pc = (char*)&P[0];

#pragma unroll
  for (int i = 0; i < 4; ++i) {
    int r = w * 4 + i;
    const float* rowp = adjb + (size_t)(q0 + r) * S + lane * 4;
    f32x4 rv[8];
    float lm = -1e30f;
#pragma unroll
    for (int kk = 0; kk < 8; ++kk) {
      rv[kk] = *(const f32x4*)(rowp + kk * 256);
      lm = fmaxf(lm, fmaxf(fmaxf(rv[kk].x, rv[kk].y), fmaxf(rv[kk].z, rv[kk].w)));
    }
#pragma unroll
    for (int off = 32; off > 0; off >>= 1) lm = fmaxf(lm, __shfl_xor(lm, off));
    float s = 0.f;
    uint32_t wbase = (uint32_t)(r * 4096 + (lane & 1) * 8);
#pragma unroll
    for (int kk = 0; kk < 8; ++kk) {
      bf16x4 pb;
      pb[0] = (bf16)__expf(rv[kk].x - lm);
      pb[1] = (bf16)__expf(rv[kk].y - lm);
      pb[2] = (bf16)__expf(rv[kk].z - lm);
      pb[3] = (bf16)__expf(rv[kk].w - lm);
      s += (float)pb[0] + (float)pb[1] + (float)pb[2] + (float)pb[3];
      uint32_t g = (uint32_t)(lane >> 1) + (uint32_t)(kk * 32);
      uint32_t gs = g ^ (uint32_t)(r & 7);
      *(bf16x4*)(Pc + wbase + gs * 16) = pb;
    }
#pragma unroll
    for (int off = 32; off > 0; off >>= 1) s += __shfl_xor(s, off);
    if (lane == 0) rsum[r] = s;
  }
  __syncthreads();

  int dl = (w << 4) + (lane & 15);
  const bf16* vrow = Vtb + (size_t)dl * S + (lane >> 4) * 8;
  uint32_t rl = (uint32_t)(lane & 15);
  uint32_t abase = rl * 4096;
  uint32_t rx = rl & 7;
  f32x4 acc0 = {0.f, 0.f, 0.f, 0.f}, acc1 = {0.f, 0.f, 0.f, 0.f};
#pragma unroll 4
  for (int k0 = 0; k0 < S; k0 += 64) {
    uint32_t g0 = (uint32_t)(k0 >> 3) + (uint32_t)(lane >> 4);
    bf16x8 a0 = *(const bf16x8*)(Pc + abase + ((g0 ^ rx) * 16));
    bf16x8 b0 = *(const bf16x8*)(vrow + k0);
    acc0 = __builtin_amdgcn_mfma_f32_16x16x32_bf16(a0, b0, acc0, 0, 0, 0);
    uint32_t g1 = g0 + 4;
    bf16x8 a1 = *(const bf16x8*)(Pc + abase + ((g1 ^ rx) * 16));
    bf16x8 b1 = *(const bf16x8*)(vrow + k0 + 32);
    acc1 = __builtin_amdgcn_mfma_f32_16x16x32_bf16(a1, b1, acc1, 0, 0, 0);
  }
  f32x4 accs = acc0 + acc1;
#pragma unroll
  for (int reg = 0; reg < 4; ++reg) {
    int m = ((lane >> 4) << 2) + reg;
    outb[(size_t)(q0 + m) * D + dl] = accs[reg] / rsum[m];
  }
}

// ---------------------------------------------------------------------------
extern "C" void kernel_launch(void* const* d_in, const int* in_sizes, int n_in,
                              void* d_out, int out_size, void* d_ws, size_t ws_size,
                              hipStream_t stream) {
  const float* Q  = (const float*)d_in[0];
  const float* Km = (const float*)d_in[1];
  const float* V  = (const float*)d_in[2];
  const float* W1 = (const float*)d_in[3];
  const float* b1 = (const float*)d_in[4];
  const float* W2 = (const float*)d_in[5];
  const float* b2 = (const float*)d_in[6];
  float* out = (float*)d_out;
  char* ws = (char*)d_ws;

  // layout: W1t 16M | W2t 16M | Qb16 2M | Kb16 2M | X (Sc bf16 / adj f32,
  // aliased) G*16M | h G*16M | [VtAll 2M if it fits].
  bf16* W1t  = (bf16*)ws;
  bf16* W2t  = (bf16*)(ws + 16777216);
  bf16* Qb16 = (bf16*)(ws + 33554432);
  bf16* Kb16 = (bf16*)(ws + 35651584);

  int G = 1;
  if (ws_size >= 306184192ULL) G = 8;        // thresholds unchanged (R7-verified)
  else if (ws_size >= 171966464ULL) G = 4;
  else if (ws_size >= 104857600ULL) G = 2;

  bf16* Sc   = (bf16*)(ws + 37748736);
  float* adj = (float*)(ws + 37748736);
  bf16* h    = (bf16*)(ws + 37748736 + (size_t)G * 16777216);

  // Hoisted all-NB Vt region (2 MB) after h, only if workspace allows;
  // otherwise fall back to per-iteration vt_cast into the dead h region.
  size_t vtOff = 37748736ULL + (size_t)G * 33554432ULL;
  bf16* VtAll = nullptr;
  if (ws_size >= vtOff + 2097152ULL) VtAll = (bf16*)(ws + vtOff);

  // One preamble dispatch: W1t + W2t + Q/K casts (+ all-NB Vt if hoisted).
  int prepBlocks = VtAll ? (6144 + NB * 32) : 6144;
  mega_prep<<<dim3(prepBlocks), 256, 0, stream>>>(
      W1, W1t, W2, W2t, Q, Qb16, Km, Kb16, V, VtAll ? VtAll : W1t);

  for (int b0 = 0; b0 < NB; b0 += G) {
    // scores = (Q @ K^T) / 8 via the specialized 2-barrier QK kernel (R17)
    qk_bt<<<dim3(S / 256, S / 128, G), 256, 0, stream>>>(
        Qb16 + (size_t)b0 * S * D, Kb16 + (size_t)b0 * S * D, Sc);
    // big MLP GEMMs, both on the verified R13 rotated schedule
    gemm256<1, 1><<<dim3(H / 256, S / 256, G), 512, 0, stream>>>(
        Sc, W1t, b1, h, 1.0f, S, H, S, (long)S * S, 0L, (long)S * H);
    gemm256<0, 0><<<dim3(S / 256, S / 256, G), 512, 0, stream>>>(
        h, W2t, b2, adj, 1.0f, S, S, H, (long)S * H, 0L, (long)S * S);
    // fused softmax + AV on MFMA
    const bf16* VtBase;
    if (VtAll) {
      VtBase = VtAll + (size_t)b0 * D * S;
    } else {
      vt_cast<<<dim3(S / 64, G), 256, 0, stream>>>(V + (size_t)b0 * S * D, h);
      VtBase = h;
    }
    smav<<<dim3(S / 16, G), 256, 0, stream>>>(
        adj, VtBase, out + (size_t)b0 * S * D, (long)S * S);
  }
}

// Round 11
// 616.657 us; speedup vs baseline: 1.0284x; 1.0284x over previous
//
#include <hip/hip_runtime.h>
#include <hip/hip_bf16.h>
#include <stdint.h>

#define S 2048
#define D 64
#define H 4096
#define NB 8

typedef __bf16 bf16;
typedef __attribute__((ext_vector_type(8))) __bf16 bf16x8;
typedef __attribute__((ext_vector_type(4))) __bf16 bf16x4;
typedef __attribute__((ext_vector_type(4))) float f32x4;

// Raw LDS-DMA, invisible to the compiler's waitcnt pass (no auto vmcnt(0)).
// M0 = wave-uniform LDS byte offset; HW adds lane*16B. (R5-verified.)
__device__ __forceinline__ void dma16_raw(const bf16* g, uint32_t m0_bytes) {
  uint32_t m0s = __builtin_amdgcn_readfirstlane(m0_bytes);
  asm volatile("s_mov_b32 m0, %1\n\t"
               "global_load_lds_dwordx4 %0, off"
               :: "v"(g), "s"(m0s) : "memory");
}

__device__ __forceinline__ uint32_t lds_off_bytes(const void* p) {
  return (uint32_t)(uintptr_t)(__attribute__((address_space(3))) const void*)p;
}

// ---------------------------------------------------------------------------
// mega_prep (R16): ONE preamble dispatch replacing {W1 transpose, W2
// transpose, Q/K cast, all-NB V transpose}. Role decode on blockIdx.x.
// ---------------------------------------------------------------------------
__global__ __launch_bounds__(256) void mega_prep(
    const float* __restrict__ W1, bf16* __restrict__ W1t,
    const float* __restrict__ W2, bf16* __restrict__ W2t,
    const float* __restrict__ Q, bf16* __restrict__ Qb,
    const float* __restrict__ Km, bf16* __restrict__ Kb,
    const float* __restrict__ V, bf16* __restrict__ VtAll) {
  __shared__ float tile[64][65];
  int b = blockIdx.x;
  int tid = threadIdx.x;
  int c4 = (tid & 15) * 4;
  int r16 = tid >> 4;

  if (b < 4096) {
    // ---- transpose+cast role (R14 vectorized body) ----
    const float* W; bf16* Wt; int K, N, x, y;
    if (b < 2048) { W = W1; Wt = W1t; K = S; N = H; x = b & 63; y = b >> 6; }
    else { int t = b - 2048; W = W2; Wt = W2t; K = H; N = S; x = t & 31; y = t >> 5; }
    int k0 = y * 64, n0 = x * 64;
#pragma unroll
    for (int i = 0; i < 4; ++i) {
      int r = i * 16 + r16;
      f32x4 v = *(const f32x4*)&W[(size_t)(k0 + r) * N + n0 + c4];
      tile[r][c4 + 0] = v.x; tile[r][c4 + 1] = v.y;
      tile[r][c4 + 2] = v.z; tile[r][c4 + 3] = v.w;
    }
    __syncthreads();
#pragma unroll
    for (int i = 0; i < 4; ++i) {
      int n = i * 16 + r16;
      bf16x4 o;
      o[0] = (bf16)tile[c4 + 0][n]; o[1] = (bf16)tile[c4 + 1][n];
      o[2] = (bf16)tile[c4 + 2][n]; o[3] = (bf16)tile[c4 + 3][n];
      *(bf16x4*)&Wt[(size_t)(n0 + n) * K + k0 + c4] = o;
    }
  } else if (b < 6144) {
    // ---- elementwise cast role (Q then K) ----
    int t = b - 4096;
    const float* x = (t >> 10) ? Km : Q;
    bf16* y = (t >> 10) ? Kb : Qb;
    int i = (t & 1023) * 256 + tid;
    f32x4 v = ((const f32x4*)x)[i];
    bf16x4 o;
    o[0] = (bf16)v.x; o[1] = (bf16)v.y; o[2] = (bf16)v.z; o[3] = (bf16)v.w;
    ((bf16x4*)y)[i] = o;
  } else {
    // ---- V transpose role (all NB batches, hoisted-Vt mode only) ----
    int t = b - 6144;  // 0..NB*32-1
    int s0 = (t & 31) * 64;
    int z = t >> 5;
    const float* Vb = V + (size_t)z * (S * D);
    bf16* Vtb = VtAll + (size_t)z * (D * S);
#pragma unroll
    for (int i = 0; i < 4; ++i) {
      int r = i * 16 + r16;  // s-row within tile
      f32x4 v = *(const f32x4*)&Vb[(size_t)(s0 + r) * D + c4];
      tile[r][c4 + 0] = v.x; tile[r][c4 + 1] = v.y;
      tile[r][c4 + 2] = v.z; tile[r][c4 + 3] = v.w;
    }
    __syncthreads();
#pragma unroll
    for (int i = 0; i < 4; ++i) {
      int n = i * 16 + r16;  // d index
      bf16x4 o;
      o[0] = (bf16)tile[c4 + 0][n]; o[1] = (bf16)tile[c4 + 1][n];
      o[2] = (bf16)tile[c4 + 2][n]; o[3] = (bf16)tile[c4 + 3][n];
      *(bf16x4*)&Vtb[(size_t)n * S + s0 + c4] = o;
    }
  }
}

// ---------------------------------------------------------------------------
// vt_cast: per-group V transpose — FALLBACK path only (workspace too small
// for the dedicated all-NB Vt region; writes into the dead h region).
// ---------------------------------------------------------------------------
__global__ __launch_bounds__(256) void vt_cast(const float* __restrict__ V,
                                               bf16* __restrict__ Vt) {
  __shared__ float tile[64][65];
  int z = blockIdx.y;
  int s0 = blockIdx.x * 64;
  const float* Vb = V + (size_t)z * (S * D);
  bf16* Vtb = Vt + (size_t)z * (D * S);
  int c4 = (threadIdx.x & 15) * 4;
  int r16 = threadIdx.x >> 4;
#pragma unroll
  for (int i = 0; i < 4; ++i) {
    int r = i * 16 + r16;
    f32x4 v = *(const f32x4*)&Vb[(size_t)(s0 + r) * D + c4];
    tile[r][c4 + 0] = v.x; tile[r][c4 + 1] = v.y;
    tile[r][c4 + 2] = v.z; tile[r][c4 + 3] = v.w;
  }
  __syncthreads();
#pragma unroll
  for (int i = 0; i < 4; ++i) {
    int n = i * 16 + r16;
    bf16x4 o;
    o[0] = (bf16)tile[c4 + 0][n]; o[1] = (bf16)tile[c4 + 1][n];
    o[2] = (bf16)tile[c4 + 2][n]; o[3] = (bf16)tile[c4 + 3][n];
    *(bf16x4*)&Vtb[(size_t)n * S + s0 + c4] = o;
  }
}

// ---------------------------------------------------------------------------
// qk_body (R17/R18): specialized QK^T GEMM body, shared by the standalone
// qk_bt kernel and the fused smav_qk kernel. Stage BOTH K-tiles up front ->
// vmcnt(6)+bar -> 32 MFMA -> vmcnt(0)+bar -> 32 MFMA -> store.
// Staging layout / swizzle / per-acc MFMA order identical to the original
// verified gemm_bt -> bit-identical numerics. Sc = (Q @ K^T) * 0.125, bf16.
// Needs 48 KiB of LDS at smc.
// ---------------------------------------------------------------------------
__device__ __forceinline__ void qk_body(char* smc, const bf16* Ab,
                                        const bf16* Btb, bf16* C,
                                        int bx, int by) {
  bf16* smem = (bf16*)smc;
  int tid = threadIdx.x;
  int lane = tid & 63;
  int w = tid >> 6;

  int m0 = by * 128, n0 = bx * 256;

  int grow = tid >> 2;
  int gcol = (((lane & 3) ^ ((lane >> 3) & 3)) * 8);
  const bf16* gA0 = Ab + (size_t)(m0 + grow) * D + gcol;
  const bf16* gA1 = gA0 + (size_t)64 * D;
  const bf16* gB0 = Btb + (size_t)(n0 + grow) * D + gcol;
  const bf16* gB1 = gB0 + (size_t)64 * D;
  const bf16* gB2 = gB0 + (size_t)128 * D;
  const bf16* gB3 = gB0 + (size_t)192 * D;

  uint32_t ldsBase = lds_off_bytes(smem);
  uint32_t wb = (uint32_t)(w * 1024);
  uint32_t mA[2], mB[2];
  mA[0] = ldsBase + wb;          mA[1] = ldsBase + 8192 + wb;
  mB[0] = ldsBase + 16384 + wb;  mB[1] = ldsBase + 32768 + wb;

  int mw = (w & 1) * 64, nw = (w >> 1) * 128;
  int lr = lane & 15;
  int ck = lane >> 4;
  int swz = (ck ^ ((lr >> 1) & 3)) * 8;
  const bf16* paBase = smem + (size_t)(mw + lr) * 32 + swz;
  const bf16* pbBase = smem + 8192 + (size_t)(nw + lr) * 32 + swz;

  f32x4 zero = {0.f, 0.f, 0.f, 0.f};
  f32x4 acc[4][8];
#pragma unroll
  for (int mt = 0; mt < 4; ++mt)
#pragma unroll
    for (int nt = 0; nt < 8; ++nt) acc[mt][nt] = zero;

#define QK_STAGE(buf, koff)                              \
  do {                                                   \
    dma16_raw(gA0 + (koff), mA[buf]);                    \
    dma16_raw(gA1 + (koff), mA[buf] + 4096);             \
    dma16_raw(gB0 + (koff), mB[buf]);                    \
    dma16_raw(gB1 + (koff), mB[buf] + 4096);             \
    dma16_raw(gB2 + (koff), mB[buf] + 8192);             \
    dma16_raw(gB3 + (koff), mB[buf] + 12288);            \
  } while (0)

  QK_STAGE(0, 0);
  QK_STAGE(1, 32);
#undef QK_STAGE

#pragma unroll
  for (int it = 0; it < 2; ++it) {
    if (it == 0)
      asm volatile("s_waitcnt vmcnt(6)\n\ts_barrier" ::: "memory");
    else
      asm volatile("s_waitcnt vmcnt(0)\n\ts_barrier" ::: "memory");
    const bf16* pa = paBase + it * 4096;
    const bf16* pb = pbBase + it * 8192;
    bf16x8 af[4], bfr[8];
#pragma unroll
    for (int mt = 0; mt < 4; ++mt) af[mt] = *(const bf16x8*)(pa + mt * (16 * 32));
#pragma unroll
    for (int nt = 0; nt < 8; ++nt) bfr[nt] = *(const bf16x8*)(pb + nt * (16 * 32));
#pragma unroll
    for (int mt = 0; mt < 4; ++mt)
#pragma unroll
      for (int nt = 0; nt < 8; ++nt)
        acc[mt][nt] = __builtin_amdgcn_mfma_f32_16x16x32_bf16(af[mt], bfr[nt],
                                                              acc[mt][nt], 0, 0, 0);
  }

  int mbase = m0 + mw + (lane >> 4) * 4;
  int nbase = n0 + nw + (lane & 15);
#pragma unroll
  for (int mt = 0; mt < 4; ++mt) {
#pragma unroll
    for (int nt = 0; nt < 8; ++nt) {
      int n = nbase + nt * 16;
#pragma unroll
      for (int reg = 0; reg < 4; ++reg) {
        int m = mbase + mt * 16 + reg;
        C[(size_t)m * S + n] = (bf16)(acc[mt][nt][reg] * 0.125f);
      }
    }
  }
}

// ---------------------------------------------------------------------------
// smav_body (R9/R18): fused softmax + attn@V on MFMA, shared body.
// Needs 64.06 KiB of LDS at u (P 64K + rsum 64B).
// ---------------------------------------------------------------------------
__device__ __forceinline__ void smav_body(char* u, const float* adjb,
                                          const bf16* Vtb, float* outb,
                                          int q0) {
  char* Pc = u;
  float* rsum = (float*)(u + 65536);
  int tid = threadIdx.x, w = tid >> 6, lane = tid & 63;

#pragma unroll
  for (int i = 0; i < 4; ++i) {
    int r = w * 4 + i;
    const float* rowp = adjb + (size_t)(q0 + r) * S + lane * 4;
    f32x4 rv[8];
    float lm = -1e30f;
#pragma unroll
    for (int kk = 0; kk < 8; ++kk) {
      rv[kk] = *(const f32x4*)(rowp + kk * 256);
      lm = fmaxf(lm, fmaxf(fmaxf(rv[kk].x, rv[kk].y), fmaxf(rv[kk].z, rv[kk].w)));
    }
#pragma unroll
    for (int off = 32; off > 0; off >>= 1) lm = fmaxf(lm, __shfl_xor(lm, off));
    float s = 0.f;
    uint32_t wbase = (uint32_t)(r * 4096 + (lane & 1) * 8);
#pragma unroll
    for (int kk = 0; kk < 8; ++kk) {
      bf16x4 pb;
      pb[0] = (bf16)__expf(rv[kk].x - lm);
      pb[1] = (bf16)__expf(rv[kk].y - lm);
      pb[2] = (bf16)__expf(rv[kk].z - lm);
      pb[3] = (bf16)__expf(rv[kk].w - lm);
      s += (float)pb[0] + (float)pb[1] + (float)pb[2] + (float)pb[3];
      uint32_t g = (uint32_t)(lane >> 1) + (uint32_t)(kk * 32);
      uint32_t gs = g ^ (uint32_t)(r & 7);
      *(bf16x4*)(Pc + wbase + gs * 16) = pb;
    }
#pragma unroll
    for (int off = 32; off > 0; off >>= 1) s += __shfl_xor(s, off);
    if (lane == 0) rsum[r] = s;
  }
  __syncthreads();

  int dl = (w << 4) + (lane & 15);
  const bf16* vrow = Vtb + (size_t)dl * S + (lane >> 4) * 8;
  uint32_t rl = (uint32_t)(lane & 15);
  uint32_t abase = rl * 4096;
  uint32_t rx = rl & 7;
  f32x4 acc0 = {0.f, 0.f, 0.f, 0.f}, acc1 = {0.f, 0.f, 0.f, 0.f};
#pragma unroll 4
  for (int k0 = 0; k0 < S; k0 += 64) {
    uint32_t g0 = (uint32_t)(k0 >> 3) + (uint32_t)(lane >> 4);
    bf16x8 a0 = *(const bf16x8*)(Pc + abase + ((g0 ^ rx) * 16));
    bf16x8 b0 = *(const bf16x8*)(vrow + k0);
    acc0 = __builtin_amdgcn_mfma_f32_16x16x32_bf16(a0, b0, acc0, 0, 0, 0);
    uint32_t g1 = g0 + 4;
    bf16x8 a1 = *(const bf16x8*)(Pc + abase + ((g1 ^ rx) * 16));
    bf16x8 b1 = *(const bf16x8*)(vrow + k0 + 32);
    acc1 = __builtin_amdgcn_mfma_f32_16x16x32_bf16(a1, b1, acc1, 0, 0, 0);
  }
  f32x4 accs = acc0 + acc1;
#pragma unroll
  for (int reg = 0; reg < 4; ++reg) {
    int m = ((lane >> 4) << 2) + reg;
    outb[(size_t)(q0 + m) * D + dl] = accs[reg] / rsum[m];
  }
}

// ---------------------------------------------------------------------------
// qk_bt: standalone QK^T dispatch (group 0 in overlap mode; all groups in
// fallback mode). grid (8, 16, G).
// ---------------------------------------------------------------------------
__global__ __launch_bounds__(256, 2) void qk_bt(const bf16* __restrict__ Qb,
                                                const bf16* __restrict__ Kb,
                                                bf16* __restrict__ Sc) {
  __shared__ __align__(16) char u[49152];
  int z = blockIdx.z;
  qk_body(u, Qb + (size_t)z * (S * D), Kb + (size_t)z * (S * D),
          Sc + (size_t)z * (S * S), blockIdx.x, blockIdx.y);
}

// ---------------------------------------------------------------------------
// smav_qk (R18): co-dispatched softmax+AV (group g) and QK^T (group g+1).
// The two phases are independent (smav reads adj/Vt/out of group g; qk
// reads Qb/Kb of group g+1 and writes the dedicated ScB region, which
// W1-gemm(g) consumed strictly earlier in-stream) -> no races, numerics
// bit-identical; qk's MFMA/store work rides in smav's bandwidth shadow.
// Role decode: blockIdx.x < 128 -> smav block; else qk block.
// Launch with x-dim 128 when there is no next group (pure smav).
// LDS: 65600-byte union (smav 64K+64; qk 48K).
// ---------------------------------------------------------------------------
__global__ __launch_bounds__(256, 2) void smav_qk(
    const float* __restrict__ adj, const bf16* __restrict__ Vt,
    float* __restrict__ out,
    const bf16* __restrict__ Qbn, const bf16* __restrict__ Kbn,
    bf16* __restrict__ ScB) {
  __shared__ __align__(16) char u[65600];
  int z = blockIdx.y;
  if (blockIdx.x < 128) {
    smav_body(u, adj + (size_t)z * (S * S), Vt + (size_t)z * (D * S),
              out + (size_t)z * (S * D), blockIdx.x * 16);
  } else {
    int f = blockIdx.x - 128;  // 0..127
    qk_body(u, Qbn + (size_t)z * (S * D), Kbn + (size_t)z * (S * D),
            ScB + (size_t)z * (S * S), f & 7, f >> 3);
  }
}

// ---------------------------------------------------------------------------
// gemm256: R13 rotated 4-barrier counted-vmcnt schedule. VERIFIED BEST:
// ~117 us, MfmaUtil 52%, 0 conflicts. Schedule-lever search CLOSED by
// measurement (R8/R10/R11/R13/R14: 46-52% across 5 structures) and by
// arithmetic: 2 blocks/CU needs <=128 VGPR/wave (4 waves/SIMD) but acc
// alone is 128 regs -> occupancy register-closed at 1 block/CU; 2M x 4N
// wave grid minimizes per-wave LDS bytes/FLOP; 3-barrier tile = WAR race;
// 32x32 shape = measured 1.26e7 conflicts. Ceiling model: MFMA floor 2483
// cyc/tile vs LDS ~2300-3000 cyc -> max ~55-62% util; measured 52%.
// Do not change fragment read pattern / stage order / vmcnt placement
// without re-measuring SQ_LDS_BANK_CONFLICT and re-deriving the R8 RAW
// invariant (at each tile-boundary vmcnt(4), exactly the two tile+2
// half-stages are outstanding).
// ---------------------------------------------------------------------------
template <int RELU, int OUTBF16>
__global__ __launch_bounds__(512, 2) void gemm256(const bf16* __restrict__ A,
                                                  const bf16* __restrict__ Bt,
                                                  const float* __restrict__ bias,
                                                  void* __restrict__ Cv,
                                                  float scale,
                                                  int M, int N, int K,
                                                  long strideA, long strideB,
                                                  long strideC) {
  __shared__ __align__(16) bf16 smem[65536];  // 128 KiB
  const char* smc = (const char*)&smem[0];

  int tid = threadIdx.x;
  int lane = tid & 63;
  int w = tid >> 6;
  int wm = w >> 2, wn = w & 3;  // 2M x 4N wave grid

  unsigned gx = gridDim.x;
  unsigned nwg = gx * gridDim.y;
  unsigned flat = blockIdx.y * gx + blockIdx.x;
  unsigned q = nwg >> 3, r = nwg & 7, xcd = flat & 7, idx = flat >> 3;
  unsigned wg = (xcd < r ? xcd * (q + 1) : r * (q + 1) + (xcd - r) * q) + idx;
  int n0 = (int)(wg % gx) * 256;
  int m0 = (int)(wg / gx) * 256;

  const bf16* Ab = A + (size_t)blockIdx.z * strideA;
  const bf16* Btb = Bt + (size_t)blockIdx.z * strideB;

  int trow = tid >> 3;
  int tg = (tid & 7) ^ (trow & 7);
  const bf16* pgA = Ab + (size_t)(m0 + trow) * K + tg * 8;
  const bf16* pgB = Btb + (size_t)(n0 + trow) * K + tg * 8;
  const size_t s64K = (size_t)K * 64;

  uint32_t ldsBase = lds_off_bytes(&smem[0]);
  uint32_t mb = ldsBase + (uint32_t)(w * 1024);

  int j = lane >> 4, b2 = (lane >> 2) & 1;
  uint32_t rbA0 = (uint32_t)(wm * 8192 + (lane & 15) * 128 +
                             ((j ^ (lane & 3)) * 16) + b2 * 64);
  uint32_t rbA1 = rbA0 ^ 64u;
  uint32_t rbB0 = (uint32_t)(65536 + wn * 4096 + (lane & 15) * 128 +
                             ((j ^ (lane & 3)) * 16) + b2 * 64);
  uint32_t rbB1 = rbB0 ^ 64u;

  f32x4 acc[8][4];
#pragma unroll
  for (int a = 0; a < 8; ++a)
#pragma unroll
    for (int b = 0; b < 2 * 2; ++b) acc[a][b] = (f32x4){0.f, 0.f, 0.f, 0.f};

  bf16x8 af[4][2];
  bf16x8 bf0[2][2];
  bf16x8 bf1[2][2];

#define STG_A(PI, HH, LL, KC) \
  dma16_raw(pgA + (size_t)(2 * (HH) + (LL)) * s64K + (KC), \
            mb + (PI) * 32768 + (HH) * 16384 + (LL) * 8192)
#define STG_B(PI, HH, LL, KC) \
  dma16_raw(pgB + (size_t)(2 * (HH) + (LL)) * s64K + (KC), \
            mb + 65536 + (PI) * 32768 + (HH) * 16384 + (LL) * 8192)
#define STAGE_AH(PI, HH, KC) do { STG_A(PI, HH, 0, KC); STG_A(PI, HH, 1, KC); } while (0)
#define STAGE_BH(PI, HH, KC) do { STG_B(PI, HH, 0, KC); STG_B(PI, HH, 1, KC); } while (0)

#define RDA(PI, QA)                                                            \
  do {                                                                        \
    _Pragma("unroll") for (int mt = 0; mt < 4; ++mt) {                        \
      af[mt][0] = *(const bf16x8*)(smc + rbA0 + ((PI) * 32768 + (QA) * 16384 + mt * 2048)); \
      af[mt][1] = *(const bf16x8*)(smc + rbA1 + ((PI) * 32768 + (QA) * 16384 + mt * 2048)); \
    }                                                                         \
  } while (0)
#define RDB(PI, QB, BF)                                                        \
  do {                                                                        \
    _Pragma("unroll") for (int nt = 0; nt < 2; ++nt) {                        \
      BF[nt][0] = *(const bf16x8*)(smc + rbB0 + ((PI) * 32768 + (QB) * 16384 + nt * 2048)); \
      BF[nt][1] = *(const bf16x8*)(smc + rbB1 + ((PI) * 32768 + (QB) * 16384 + nt * 2048)); \
    }                                                                         \
  } while (0)

#define MFMA_Q(QA, QB, BF)                                                     \
  do {                                                                        \
    __builtin_amdgcn_s_setprio(1);                                            \
    _Pragma("unroll") for (int mt = 0; mt < 4; ++mt)                          \
      _Pragma("unroll") for (int nt = 0; nt < 2; ++nt) {                      \
        f32x4 c = acc[(QA) * 4 + mt][(QB) * 2 + nt];                          \
        c = __builtin_amdgcn_mfma_f32_16x16x32_bf16(af[mt][0], BF[nt][0], c, 0, 0, 0); \
        c = __builtin_amdgcn_mfma_f32_16x16x32_bf16(af[mt][1], BF[nt][1], c, 0, 0, 0); \
        acc[(QA) * 4 + mt][(QB) * 2 + nt] = c;                                \
      }                                                                       \
    __builtin_amdgcn_s_setprio(0);                                            \
  } while (0)

#define BAR() asm volatile("s_barrier" ::: "memory")
#define VMC4() asm volatile("s_waitcnt vmcnt(4)" ::: "memory")

#define TILE2(PI, TT)                                              \
  do {                                                             \
    int c1 = ((TT) + 1 < NT ? (TT) + 1 : NT - 1) * 64;             \
    int c2 = ((TT) + 2 < NT ? (TT) + 2 : NT - 1) * 64;             \
    MFMA_Q(0, 0, bf0);                                             \
    RDB(PI, 1, bf1);                                               \
    STAGE_BH((PI) ^ 1, 0, c1);                                     \
    BAR();                                                         \
    MFMA_Q(0, 1, bf1);                                             \
    RDA(PI, 1);                                                    \
    STAGE_AH(PI, 0, c2);                                           \
    BAR();                                                         \
    STAGE_BH(PI, 1, c2);                                           \
    MFMA_Q(1, 1, bf1);                                             \
    VMC4();                                                        \
    BAR();                                                         \
    MFMA_Q(1, 0, bf0);                                             \
    if ((TT) + 1 < NT) {                                           \
      RDA((PI) ^ 1, 0);                                            \
      RDB((PI) ^ 1, 0, bf0);                                       \
      STAGE_AH(PI, 1, c2);                                         \
      BAR();                                                       \
    }                                                              \
  } while (0)

  STAGE_AH(0, 0, 0);
  STAGE_BH(0, 1, 0);
  STAGE_AH(0, 1, 0);
  STAGE_BH(0, 0, 0);
  STAGE_AH(1, 0, 64);
  STAGE_BH(1, 1, 64);
  asm volatile("s_waitcnt vmcnt(4)\n\ts_barrier" ::: "memory");

  const int NT = K / 64;

  RDA(0, 0);
  RDB(0, 0, bf0);
  STAGE_AH(1, 1, 64);
  BAR();

  for (int T = 0; T < NT; T += 2) {
    TILE2(0, T);
    TILE2(1, T + 1);
  }
#undef TILE2
#undef VMC4
#undef BAR
#undef MFMA_Q
#undef RDB
#undef RDA
#undef STAGE_BH
#undef STAGE_AH
#undef STG_B
#undef STG_A

  asm volatile("s_waitcnt vmcnt(0)" ::: "memory");

  int rowb = m0 + wm * 64 + ((lane >> 4) << 2);
  int colb = n0 + wn * 32 + (lane & 15);
#pragma unroll
  for (int fn = 0; fn < 4; ++fn) {
    int n = colb + (fn >> 1) * 128 + (fn & 1) * 16;
    float bv = bias ? bias[n] : 0.f;
#pragma unroll
    for (int fm = 0; fm < 8; ++fm) {
      int mrow = rowb + (fm >> 2) * 128 + (fm & 3) * 16;
#pragma unroll
      for (int reg = 0; reg < 4; ++reg) {
        float v = acc[fm][fn][reg] * scale + bv;
        if (RELU) v = fmaxf(v, 0.f);
        int m = mrow + reg;
        if (OUTBF16) {
          bf16* C = (bf16*)Cv + (size_t)blockIdx.z * strideC;
          C[(size_t)m * N + n] = (bf16)v;
        } else {
          float* C = (float*)Cv + (size_t)blockIdx.z * strideC;
          C[(size_t)m * N + n] = v;
        }
      }
    }
  }
}

// ---------------------------------------------------------------------------
extern "C" void kernel_launch(void* const* d_in, const int* in_sizes, int n_in,
                              void* d_out, int out_size, void* d_ws, size_t ws_size,
                              hipStream_t stream) {
  const float* Q  = (const float*)d_in[0];
  const float* Km = (const float*)d_in[1];
  const float* V  = (const float*)d_in[2];
  const float* W1 = (const float*)d_in[3];
  const float* b1 = (const float*)d_in[4];
  const float* W2 = (const float*)d_in[5];
  const float* b2 = (const float*)d_in[6];
  float* out = (float*)d_out;
  char* ws = (char*)d_ws;

  // layout: W1t 16M | W2t 16M | Qb16 2M | Kb16 2M | X (Sc bf16 / adj f32,
  // aliased) G*16M | h G*16M | [VtAll 2M] | [ScB G*8M, overlap tier].
  bf16* W1t  = (bf16*)ws;
  bf16* W2t  = (bf16*)(ws + 16777216);
  bf16* Qb16 = (bf16*)(ws + 33554432);
  bf16* Kb16 = (bf16*)(ws + 35651584);

  int G = 1;
  if (ws_size >= 306184192ULL) G = 8;        // thresholds unchanged (R7-verified)
  else if (ws_size >= 171966464ULL) G = 4;
  else if (ws_size >= 104857600ULL) G = 2;

  bf16* Sc   = (bf16*)(ws + 37748736);
  float* adj = (float*)(ws + 37748736);
  bf16* h    = (bf16*)(ws + 37748736 + (size_t)G * 16777216);

  // Tier 2: hoisted all-NB Vt region (2 MB) after h.
  size_t vtOff = 37748736ULL + (size_t)G * 33554432ULL;
  bf16* VtAll = nullptr;
  if (ws_size >= vtOff + 2097152ULL) VtAll = (bf16*)(ws + vtOff);

  // Tier 3: dedicated ScB (G*8M) after VtAll -> smav/qk co-dispatch.
  size_t sbOff = vtOff + 2097152ULL;
  bf16* ScB = nullptr;
  if (VtAll && ws_size >= sbOff + (size_t)G * 8388608ULL)
    ScB = (bf16*)(ws + sbOff);

  // One preamble dispatch: W1t + W2t + Q/K casts (+ all-NB Vt if hoisted).
  int prepBlocks = VtAll ? (6144 + NB * 32) : 6144;
  mega_prep<<<dim3(prepBlocks), 256, 0, stream>>>(
      W1, W1t, W2, W2t, Q, Qb16, Km, Kb16, V, VtAll ? VtAll : W1t);

  const int ngroups = NB / G;
  if (ScB) {
    // Overlap tier: Sc always lives in ScB; qk for group g+1 co-dispatched
    // with smav of group g (smav_qk). Timeline per group: W1-gemm consumes
    // ScB -> W2-gemm writes adj -> fused {smav reads adj; qk refills ScB}.
    qk_bt<<<dim3(S / 256, S / 128, G), 256, 0, stream>>>(Qb16, Kb16, ScB);
    for (int g = 0; g < ngroups; ++g) {
      int b0 = g * G;
      gemm256<1, 1><<<dim3(H / 256, S / 256, G), 512, 0, stream>>>(
          ScB, W1t, b1, h, 1.0f, S, H, S, (long)S * S, 0L, (long)S * H);
      gemm256<0, 0><<<dim3(S / 256, S / 256, G), 512, 0, stream>>>(
          h, W2t, b2, adj, 1.0f, S, S, H, (long)S * H, 0L, (long)S * S);
      int hasNext = (g + 1 < ngroups);
      int nb0 = (b0 + G) % NB;  // dummy-safe when !hasNext
      smav_qk<<<dim3(hasNext ? 256 : 128, G), 256, 0, stream>>>(
          adj, VtAll + (size_t)b0 * D * S, out + (size_t)b0 * S * D,
          Qb16 + (size_t)nb0 * S * D, Kb16 + (size_t)nb0 * S * D, ScB);
    }
  } else {
    // Fallback tiers (R16/R17 behavior): Sc aliases the adj region.
    for (int b0 = 0; b0 < NB; b0 += G) {
      qk_bt<<<dim3(S / 256, S / 128, G), 256, 0, stream>>>(
          Qb16 + (size_t)b0 * S * D, Kb16 + (size_t)b0 * S * D, Sc);
      gemm256<1, 1><<<dim3(H / 256, S / 256, G), 512, 0, stream>>>(
          Sc, W1t, b1, h, 1.0f, S, H, S, (long)S * S, 0L, (long)S * H);
      gemm256<0, 0><<<dim3(S / 256, S / 256, G), 512, 0, stream>>>(
          h, W2t, b2, adj, 1.0f, S, S, H, (long)S * H, 0L, (long)S * S);
      const bf16* VtBase;
      if (VtAll) {
        VtBase = VtAll + (size_t)b0 * D * S;
      } else {
        vt_cast<<<dim3(S / 64, G), 256, 0, stream>>>(V + (size_t)b0 * S * D, h);
        VtBase = h;
      }
      smav_qk<<<dim3(128, G), 256, 0, stream>>>(
          adj, VtBase, out + (size_t)b0 * S * D, Qb16, Kb16, (bf16*)ws);
    }
  }
}